// Round 1
// baseline (63.629 us; speedup 1.0000x reference)
//
#include <hip/hip_runtime.h>

#define CIN  32
#define COUT 64
#define HH   64
#define WW   64
#define NB   4
#define TILE 16
#define HALO 18        // TILE + 2 (3x3, pad 1)
#define CPT  8         // output channels per block (and per thread)

__global__ __launch_bounds__(256)
void aeg_conv_kernel(const float* __restrict__ x,
                     const float* __restrict__ weight,
                     const float* __restrict__ conv_w,
                     const float* __restrict__ conv_b,
                     float* __restrict__ out)
{
    __shared__ float sx[CIN * HALO * HALO];   // 41472 B

    const int tid = threadIdx.x;
    const int j0 = blockIdx.x * TILE;
    const int i0 = blockIdx.y * TILE;
    const int bz = blockIdx.z;                // n * (COUT/CPT) + co_chunk
    const int n   = bz >> 3;                  // COUT/CPT == 8
    const int co0 = (bz & 7) * CPT;

    const float* xn = x + (size_t)n * (CIN * HH * WW);

    // ---- stage x tile (+1 halo all sides) into LDS, zero-fill padding ----
    for (int idx = tid; idx < CIN * HALO * HALO; idx += 256) {
        int ci  = idx / (HALO * HALO);
        int rem = idx - ci * (HALO * HALO);
        int r   = rem / HALO;
        int c   = rem - r * HALO;
        int gi  = i0 - 1 + r;
        int gj  = j0 - 1 + c;
        float v = 0.0f;
        if ((unsigned)gi < (unsigned)HH && (unsigned)gj < (unsigned)WW)
            v = xn[ci * (HH * WW) + gi * WW + gj];
        sx[idx] = v;
    }
    __syncthreads();

    const int tj = tid & 15;
    const int ti = tid >> 4;
    const int i  = i0 + ti;
    const int j  = j0 + tj;
    const bool podd = ((i + j) & 1) != 0;     // parity of (i+j)

    float aeg[CPT];
    float cv[CPT];
    #pragma unroll
    for (int c = 0; c < CPT; ++c) { aeg[c] = 0.0f; cv[c] = 0.0f; }

    const float* wbase = weight + (size_t)(co0 * CIN) * 9;
    const float* cbase = conv_w + (size_t)(co0 * CIN) * 9;

    for (int ci = 0; ci < CIN; ++ci) {
        // 9 taps for this input channel (zero-padded neighborhood)
        float t[9];
        #pragma unroll
        for (int ki = 0; ki < 3; ++ki)
            #pragma unroll
            for (int kj = 0; kj < 3; ++kj)
                t[ki * 3 + kj] = sx[ci * (HALO * HALO) + (ti + ki) * HALO + (tj + kj)];

        #pragma unroll
        for (int c = 0; c < CPT; ++c) {
            const float* ya = wbase + (size_t)(c * CIN + ci) * 9;  // aeg weights (uniform addr -> s_load)
            const float* yc = cbase + (size_t)(c * CIN + ci) * 9;  // conv weights
            float r = 0.0f;
            #pragma unroll
            for (int k = 0; k < 9; ++k) {
                float yv = ya[k];
                float tv = t[k];
                // (i+j+k) even: r=(r+t)*y ; odd: r=(r+y)*t
                // both equal r*b + t*y with b = odd ? t : y   (branch-free)
                bool stepodd = podd ^ ((k & 1) != 0);
                float b = stepodd ? tv : yv;
                r = fmaf(r, b, tv * yv);
                cv[c] = fmaf(tv, yc[k], cv[c]);
            }
            aeg[c] += r;
        }
    }

    // ---- epilogue: sigmoid(aeg) * (conv + bias) ----
    #pragma unroll
    for (int c = 0; c < CPT; ++c) {
        int co = co0 + c;
        float conv = cv[c] + conv_b[co];
        float sg = 1.0f / (1.0f + __expf(-aeg[c]));
        out[(((size_t)n * COUT + co) * HH + i) * WW + j] = sg * conv;
    }
}

extern "C" void kernel_launch(void* const* d_in, const int* in_sizes, int n_in,
                              void* d_out, int out_size, void* d_ws, size_t ws_size,
                              hipStream_t stream) {
    const float* x      = (const float*)d_in[0];
    const float* weight = (const float*)d_in[1];
    const float* conv_w = (const float*)d_in[2];
    const float* conv_b = (const float*)d_in[3];
    float* out = (float*)d_out;

    dim3 grid(WW / TILE, HH / TILE, NB * (COUT / CPT));  // 4 x 4 x 32 = 512 blocks
    aeg_conv_kernel<<<grid, 256, 0, stream>>>(x, weight, conv_w, conv_b, out);
}

// Round 2
// 56.083 us; speedup vs baseline: 1.1346x; 1.1346x over previous
//
#include <hip/hip_runtime.h>

#define CIN   32
#define COUT  64
#define HH    64
#define WW    64
#define NB    4
#define TH    4              // tile rows per block (full 64-wide rows)
#define HR    (TH + 2)       // halo rows = 6
#define SW    66             // padded row width (1 + 64 + 1)
#define G     16             // input channels staged per LDS round
#define CPT   4              // output channels per thread/block

__global__ __launch_bounds__(256, 4)
void aeg_conv_kernel(const float* __restrict__ x,
                     const float* __restrict__ weight,
                     const float* __restrict__ conv_w,
                     const float* __restrict__ conv_b,
                     float* __restrict__ out)
{
    __shared__ float sx[G * HR * SW];   // 16*6*66*4 = 25344 B

    const int tid = threadIdx.x;
    const int i0  = blockIdx.x * TH;    // tile top row
    const int n   = blockIdx.y;
    const int co0 = blockIdx.z * CPT;

    const int tj = tid & 63;            // column (wave = one full row -> conflict-free LDS,
    const int ti = tid >> 6;            // row within tile      coalesced loads/stores)
    const int i  = i0 + ti;
    const bool podd = ((i + tj) & 1) != 0;

    const float* xn = x + (size_t)n * (CIN * HH * WW);

    float aeg[CPT], cv[CPT];
    #pragma unroll
    for (int c = 0; c < CPT; ++c) { aeg[c] = 0.0f; cv[c] = 0.0f; }

    for (int g = 0; g < CIN; g += G) {
        __syncthreads();                // protect sx from previous round's readers
        // ---- stage G channels of the row-tile (+1 halo row top/bottom, zero col pads) ----
        for (int idx = tid; idx < G * HR * SW; idx += 256) {
            int ci  = idx / (HR * SW);
            int rem = idx - ci * (HR * SW);
            int r   = rem / SW;
            int c   = rem - r * SW;
            int gi  = i0 - 1 + r;
            int gj  = c - 1;
            float v = 0.0f;
            if ((unsigned)gi < (unsigned)HH && (unsigned)gj < (unsigned)WW)
                v = xn[(g + ci) * (HH * WW) + gi * WW + gj];
            sx[idx] = v;
        }
        __syncthreads();

        #pragma unroll 2
        for (int cl = 0; cl < G; ++cl) {
            const int ci = g + cl;
            // 9 taps: all offsets are compile-time immediates off one base
            float t[9];
            #pragma unroll
            for (int ki = 0; ki < 3; ++ki)
                #pragma unroll
                for (int kj = 0; kj < 3; ++kj)
                    t[ki * 3 + kj] = sx[cl * (HR * SW) + (ti + ki) * SW + (tj + kj)];

            #pragma unroll
            for (int c = 0; c < CPT; ++c) {
                const float* ya = weight + ((size_t)(co0 + c) * CIN + ci) * 9;  // uniform -> s_load
                const float* yc = conv_w + ((size_t)(co0 + c) * CIN + ci) * 9;
                float r = 0.0f;
                #pragma unroll
                for (int k = 0; k < 9; ++k) {
                    float yv = ya[k];
                    float tv = t[k];
                    // (i+j+k) even: r=(r+t)*y ; odd: r=(r+y)*t ; both = r*b + t*y
                    bool stepodd = podd ^ ((k & 1) != 0);
                    float b = stepodd ? tv : yv;
                    r = fmaf(r, b, tv * yv);
                    cv[c] = fmaf(tv, yc[k], cv[c]);
                }
                aeg[c] += r;
            }
        }
    }

    // ---- epilogue: sigmoid(aeg) * (conv + bias) ----
    #pragma unroll
    for (int c = 0; c < CPT; ++c) {
        int co = co0 + c;
        float conv = cv[c] + conv_b[co];
        float sg = 1.0f / (1.0f + __expf(-aeg[c]));
        out[(((size_t)n * COUT + co) * HH + i) * WW + tj] = sg * conv;
    }
}

extern "C" void kernel_launch(void* const* d_in, const int* in_sizes, int n_in,
                              void* d_out, int out_size, void* d_ws, size_t ws_size,
                              hipStream_t stream) {
    const float* x      = (const float*)d_in[0];
    const float* weight = (const float*)d_in[1];
    const float* conv_w = (const float*)d_in[2];
    const float* conv_b = (const float*)d_in[3];
    float* out = (float*)d_out;

    dim3 grid(HH / TH, NB, COUT / CPT);   // 16 x 4 x 16 = 1024 blocks
    aeg_conv_kernel<<<grid, 256, 0, stream>>>(x, weight, conv_w, conv_b, out);
}

// Round 4
// 46.796 us; speedup vs baseline: 1.3597x; 1.1985x over previous
//
#include <hip/hip_runtime.h>

#define CIN   32
#define COUT  64
#define HH    64
#define WW    64
#define NB    4
#define TH    2              // rows per block (1 row per wave)
#define HR    (TH + 2)       // 4 halo rows
#define SW    72             // row stride (image col c at dword c+4; halos at 3 and 68)
#define G     16             // input channels per LDS round
#define CPT   4              // output channels per thread

__global__ __launch_bounds__(128, 4)
void aeg_conv_kernel(const float* __restrict__ x,
                     const float* __restrict__ weight,
                     const float* __restrict__ conv_w,
                     const float* __restrict__ conv_b,
                     float* __restrict__ out)
{
    __shared__ float sx[HR * G * SW];   // 4*16*72*4 = 18432 B

    const int tid = threadIdx.x;
    const int i0  = blockIdx.x * TH;
    const int n   = blockIdx.y;
    const int co0 = blockIdx.z * CPT;

    const int tj = tid & 63;            // column; wave = one row
    const int ti = tid >> 6;            // row within tile (0..1)
    const int i  = i0 + ti;
    const bool podd = ((i + tj) & 1) != 0;

    const float* xn = x + (size_t)n * (CIN * HH * WW);

    // halo columns (image cols -1 and 64 -> dwords 3 and 68) are always zero: write once
    {
        int pair = tid >> 1;                 // 0..63 = (r, cl)
        int col  = (tid & 1) ? 68 : 3;
        sx[pair * SW + col] = 0.0f;
    }

    float aeg[CPT], cv[CPT];
    #pragma unroll
    for (int c = 0; c < CPT; ++c) { aeg[c] = 0.0f; cv[c] = 0.0f; }

    // image col c lives at dword c+4; tap kj needs col tj-1+kj -> dword tj+3+kj
    const int vbase = ti * (G * SW) + 3 + tj;

    for (int g = 0; g < CIN; g += G) {
        __syncthreads();                // readers of previous round done (also covers halo writes)
        // ---- stage: 8 iters of float4 load + b128 LDS write, shift-only addressing ----
        #pragma unroll
        for (int it = 0; it < 8; ++it) {
            int idx   = it * 128 + tid;       // 0..1023
            int pair  = idx >> 4;             // (r*16 + cl), 0..63
            int lane4 = idx & 15;             // 16B chunk within row
            int r     = pair >> 4;
            int cl    = pair & 15;
            int gi    = i0 - 1 + r;
            float4 v = make_float4(0.f, 0.f, 0.f, 0.f);
            if ((unsigned)gi < (unsigned)HH)
                v = *(const float4*)&xn[(g + cl) * (HH * WW) + gi * WW + lane4 * 4];
            *(float4*)&sx[pair * SW + 4 + lane4 * 4] = v;
        }
        __syncthreads();

        #pragma unroll 2
        for (int cl = 0; cl < G; ++cl) {
            const int ci = g + cl;
            // 9 taps: base VGPR + compile-time immediate offsets
            float t[9];
            #pragma unroll
            for (int ki = 0; ki < 3; ++ki)
                #pragma unroll
                for (int kj = 0; kj < 3; ++kj)
                    t[ki * 3 + kj] = sx[vbase + (ki * G + cl) * SW + kj];

            #pragma unroll
            for (int c = 0; c < CPT; ++c) {
                const float* ya = weight + ((size_t)(co0 + c) * CIN + ci) * 9;  // uniform -> s_load
                const float* yc = conv_w + ((size_t)(co0 + c) * CIN + ci) * 9;
                float r = 0.0f;
                #pragma unroll
                for (int k = 0; k < 9; ++k) {
                    float yv = ya[k];
                    float tv = t[k];
                    // (i+j+k) even: r=(r+t)*y ; odd: r=(r+y)*t ; both = r*b + t*y
                    bool stepodd = podd ^ ((k & 1) != 0);
                    float b = stepodd ? tv : yv;
                    r = fmaf(r, b, tv * yv);
                    cv[c] = fmaf(tv, yc[k], cv[c]);
                }
                aeg[c] += r;
            }
        }
    }

    // ---- epilogue: sigmoid(aeg) * (conv + bias) ----
    #pragma unroll
    for (int c = 0; c < CPT; ++c) {
        int co = co0 + c;
        float conv = cv[c] + conv_b[co];
        float sg = 1.0f / (1.0f + __expf(-aeg[c]));
        out[(((size_t)n * COUT + co) * HH + i) * WW + tj] = sg * conv;
    }
}

extern "C" void kernel_launch(void* const* d_in, const int* in_sizes, int n_in,
                              void* d_out, int out_size, void* d_ws, size_t ws_size,
                              hipStream_t stream) {
    const float* x      = (const float*)d_in[0];
    const float* weight = (const float*)d_in[1];
    const float* conv_w = (const float*)d_in[2];
    const float* conv_b = (const float*)d_in[3];
    float* out = (float*)d_out;

    dim3 grid(HH / TH, NB, COUT / CPT);   // 32 x 4 x 16 = 2048 blocks
    aeg_conv_kernel<<<grid, 128, 0, stream>>>(x, weight, conv_w, conv_b, out);
}

// Round 5
// 40.376 us; speedup vs baseline: 1.5759x; 1.1590x over previous
//
#include <hip/hip_runtime.h>

#define CIN   32
#define COUT  64
#define HH    64
#define WW    64
#define NB    4
#define TH    4              // rows per block (1 row per wave, 4 waves)
#define HR    (TH + 2)       // 6 halo rows
#define SW    72             // row stride (image col c at dword c+4; halos at 3 and 68)
#define G     8              // input channels per LDS round
#define CPT   4              // output channels per thread
#define WPAD  12             // padded dwords per 9-weight group (16B-aligned groups)

__global__ __launch_bounds__(256, 4)
void aeg_conv_kernel(const float* __restrict__ x,
                     const float* __restrict__ weight,
                     const float* __restrict__ conv_w,
                     const float* __restrict__ conv_b,
                     float* __restrict__ out)
{
    __shared__ float sx[HR * G * SW];            // 6*8*72*4  = 13824 B
    __shared__ float sw[2 * CPT * CIN * WPAD];   // 2*4*32*12*4 = 12288 B

    const int tid = threadIdx.x;
    const int i0  = blockIdx.x * TH;
    const int n   = blockIdx.y;
    const int co0 = blockIdx.z * CPT;

    const int tj = tid & 63;            // column; wave = one full row
    const int ti = tid >> 6;            // row within tile (0..3)
    const int i  = i0 + ti;
    const bool podd = ((i + tj) & 1) != 0;

    const float* xn = x + (size_t)n * (CIN * HH * WW);

    // halo columns (image cols -1 and 64 -> dwords 3 and 68) are always zero: write once
    if (tid < HR * G * 2) {
        int pair = tid >> 1;
        int col  = (tid & 1) ? 68 : 3;
        sx[pair * SW + col] = 0.0f;
    }

    // ---- stage this block's weight slice into LDS (256 groups, 1 per thread) ----
    {
        int s  = tid >> 7;              // 0 = aeg weight, 1 = conv weight
        int c2 = (tid >> 5) & 3;        // co within chunk
        int ci = tid & 31;
        const float* src = (s ? conv_w : weight) + ((size_t)(co0 + c2) * CIN + ci) * 9;
        float* dst = &sw[((s * CPT + c2) * CIN + ci) * WPAD];
        #pragma unroll
        for (int k = 0; k < 9; ++k) dst[k] = src[k];
    }

    float aeg[CPT], cv[CPT];
    #pragma unroll
    for (int c = 0; c < CPT; ++c) { aeg[c] = 0.0f; cv[c] = 0.0f; }

    // image col c lives at dword c+4; tap kj needs col tj-1+kj -> dword tj+3+kj
    const int vbase = ti * (G * SW) + 3 + tj;

    for (int g = 0; g < CIN; g += G) {
        __syncthreads();                // previous round's readers done (also covers init writes)
        // ---- stage G channels x HR rows: 3 iters of float4 load + b128 LDS write ----
        #pragma unroll
        for (int it = 0; it < 3; ++it) {
            int idx   = it * 256 + tid;       // 0..767
            int pair  = idx >> 4;             // r*G + cl, 0..47
            int lane4 = idx & 15;             // 16B chunk within row
            int r     = pair >> 3;
            int cl    = pair & 7;
            int gi    = i0 - 1 + r;
            float4 v = make_float4(0.f, 0.f, 0.f, 0.f);
            if ((unsigned)gi < (unsigned)HH)
                v = *(const float4*)&xn[(g + cl) * (HH * WW) + gi * WW + lane4 * 4];
            *(float4*)&sx[pair * SW + 4 + lane4 * 4] = v;
        }
        __syncthreads();

        #pragma unroll 2
        for (int cl = 0; cl < G; ++cl) {
            const int ci = g + cl;
            // 9 taps: base VGPR + compile-time immediate offsets, conflict-free
            float t[9];
            #pragma unroll
            for (int ki = 0; ki < 3; ++ki)
                #pragma unroll
                for (int kj = 0; kj < 3; ++kj)
                    t[ki * 3 + kj] = sx[vbase + (ki * G + cl) * SW + kj];

            #pragma unroll
            for (int c = 0; c < CPT; ++c) {
                // weights from LDS: 16B-aligned groups, all-lane broadcast reads
                float wA[12], wC[12];
                const float* pa = &sw[((size_t)c * CIN + ci) * WPAD];
                const float* pc = &sw[((size_t)(CPT + c) * CIN + ci) * WPAD];
                *(float4*)&wA[0] = *(const float4*)&pa[0];
                *(float4*)&wA[4] = *(const float4*)&pa[4];
                *(float4*)&wA[8] = *(const float4*)&pa[8];
                *(float4*)&wC[0] = *(const float4*)&pc[0];
                *(float4*)&wC[4] = *(const float4*)&pc[4];
                *(float4*)&wC[8] = *(const float4*)&pc[8];

                float r = 0.0f;
                #pragma unroll
                for (int k = 0; k < 9; ++k) {
                    float yv = wA[k];
                    float tv = t[k];
                    // (i+j+k) even: r=(r+t)*y ; odd: r=(r+y)*t ; both = r*b + t*y
                    bool stepodd = podd ^ ((k & 1) != 0);
                    float b = stepodd ? tv : yv;
                    r = fmaf(r, b, tv * yv);
                    cv[c] = fmaf(tv, wC[k], cv[c]);
                }
                aeg[c] += r;
            }
        }
    }

    // ---- epilogue: sigmoid(aeg) * (conv + bias) ----
    #pragma unroll
    for (int c = 0; c < CPT; ++c) {
        int co = co0 + c;
        float conv = cv[c] + conv_b[co];
        float sg = 1.0f / (1.0f + __expf(-aeg[c]));
        out[(((size_t)n * COUT + co) * HH + i) * WW + tj] = sg * conv;
    }
}

extern "C" void kernel_launch(void* const* d_in, const int* in_sizes, int n_in,
                              void* d_out, int out_size, void* d_ws, size_t ws_size,
                              hipStream_t stream) {
    const float* x      = (const float*)d_in[0];
    const float* weight = (const float*)d_in[1];
    const float* conv_w = (const float*)d_in[2];
    const float* conv_b = (const float*)d_in[3];
    float* out = (float*)d_out;

    dim3 grid(HH / TH, NB, COUT / CPT);   // 16 x 4 x 16 = 1024 blocks
    aeg_conv_kernel<<<grid, 256, 0, stream>>>(x, weight, conv_w, conv_b, out);
}